// Round 6
// baseline (509.348 us; speedup 1.0000x reference)
//
#include <hip/hip_runtime.h>
#include <cstdint>
#include <cstddef>

#define Bn   128
#define Rn   500
#define Nn   500
#define Kn   10
#define En   128
#define H1n  640
#define KEn  1280
#define Mn   (Bn * Rn)   // 64000 rows

typedef short s16x8 __attribute__((ext_vector_type(8)));
typedef float f32x4 __attribute__((ext_vector_type(4)));

// fp32 -> bf16 round-to-nearest-even (finite inputs)
__device__ __forceinline__ unsigned short f2bf(float x) {
    union { float f; unsigned int u; } v; v.f = x;
    unsigned int r = v.u + 0x7fffu + ((v.u >> 16) & 1u);
    return (unsigned short)(r >> 16);
}
__device__ __forceinline__ float bf2f(unsigned short u) {
    union { unsigned int u; float f; } v; v.u = ((unsigned int)u) << 16;
    return v.f;
}
// async 16B global->LDS (wave-uniform LDS base + lane*16)
__device__ __forceinline__ void gl2lds16(const void* g, void* l) {
    __builtin_amdgcn_global_load_lds(
        (const __attribute__((address_space(1))) unsigned int*)g,
        (__attribute__((address_space(3))) unsigned int*)l, 16, 0, 0);
}
// Pipeline waits: vmcnt(4) = oldest stage (4 DMAs) complete, next stage still in
// flight across the barrier (AITER-style). Raw s_barrier: no compiler-inserted
// vmcnt(0) drain. Safety: iter-(k-1) ds_reads are consumed before each wave can
// issue its iter-(k-1) MFMAs (compiler lgkm waits), hence before barrier k.
__device__ __forceinline__ void wait_vm4() { asm volatile("s_waitcnt vmcnt(4)" ::: "memory"); }
__device__ __forceinline__ void wait_vm0() { asm volatile("s_waitcnt vmcnt(0)" ::: "memory"); }
__device__ __forceinline__ void barrier_raw() { asm volatile("s_barrier" ::: "memory"); }

// ---------------- kernel 1: fp32 -> bf16 conversions (encoded, w1, w2) ----------------
__global__ void convw_kernel(const float* __restrict__ enc, const float* __restrict__ w1,
                             const float* __restrict__ w2,
                             unsigned short* __restrict__ encb, unsigned short* __restrict__ w1b,
                             unsigned short* __restrict__ w2b) {
    int i = blockIdx.x * 256 + threadIdx.x;   // float4 group index
    if (i < (Bn * Nn * En) / 4) {
        float4 v = ((const float4*)enc)[i];
        ushort4 o; o.x = f2bf(v.x); o.y = f2bf(v.y); o.z = f2bf(v.z); o.w = f2bf(v.w);
        ((ushort4*)encb)[i] = o;
    }
    if (i < (H1n * KEn) / 4) {
        float4 v = ((const float4*)w1)[i];
        ushort4 o; o.x = f2bf(v.x); o.y = f2bf(v.y); o.z = f2bf(v.z); o.w = f2bf(v.w);
        ((ushort4*)w1b)[i] = o;
    }
    if (i < (En * H1n) / 4) {
        float4 v = ((const float4*)w2)[i];
        ushort4 o; o.x = f2bf(v.x); o.y = f2bf(v.y); o.z = f2bf(v.z); o.w = f2bf(v.w);
        ((ushort4*)w2b)[i] = o;
    }
}

// ---------------- kernel 2: fused top-K + pad-avg mean ----------------
__global__ __launch_bounds__(256) void select_kernel(const int* __restrict__ current,
                            const float* __restrict__ distance,
                            const float* __restrict__ masked,
                            const unsigned short* __restrict__ encb,
                            int* __restrict__ idx_out,
                            unsigned short* __restrict__ meanbb) {
    const int row  = blockIdx.x * 4 + (threadIdx.x >> 6);
    const int lane = threadIdx.x & 63;
    const int b    = row / Rn;
    const int cur  = current[row];
    const unsigned int* drow = (const unsigned int*)(distance + ((size_t)b * Nn + cur) * Nn);
    const unsigned int* mrow = (const unsigned int*)(masked + (size_t)row * Nn);

    unsigned long long key[8];
#pragma unroll
    for (int i = 0; i < 8; ++i) {
        int nn = lane + 64 * i;
        unsigned int fb = 0x7F800000u;            // +inf
        if (nn < Nn) {
            unsigned int m = mrow[nn];
            unsigned int d = drow[nn];
            fb = (m == 0xFF800000u) ? 0x7F800000u : d;   // visited -> +inf
        }
        key[i] = ((unsigned long long)fb << 32) | (unsigned int)nn;
    }

    int ids[Kn];
    int myid = Nn;
#pragma unroll
    for (int it = 0; it < Kn; ++it) {
        unsigned long long bk = key[0];
#pragma unroll
        for (int i = 1; i < 8; ++i) bk = (key[i] < bk) ? key[i] : bk;
#pragma unroll
        for (int off = 1; off < 64; off <<= 1) {
            unsigned long long ok = __shfl_xor(bk, off);
            bk = (ok < bk) ? ok : bk;
        }
        const int wid = ((bk >> 32) == 0x7F800000u) ? Nn : (int)(bk & 0xffffffffu);
        ids[it] = wid;
        if (lane == it) myid = wid;
#pragma unroll
        for (int i = 0; i < 8; ++i)
            if (key[i] == bk) key[i] = 0x7F800000FFFFFFFFull;
    }
    if (lane < Kn) idx_out[row * Kn + lane] = myid;

    const unsigned int* encu = (const unsigned int*)(encb + (size_t)b * Nn * En);
    float s0 = 0.f, s1 = 0.f; int cnt = 0;
#pragma unroll
    for (int k = 0; k < Kn; ++k) {
        const int id = ids[k];
        if (id < Nn) {
            unsigned int u = encu[id * (En / 2) + lane];
            s0 += bf2f((unsigned short)(u & 0xffffu));
            s1 += bf2f((unsigned short)(u >> 16));
            cnt++;
        }
    }
    float m0 = 0.f, m1 = 0.f;
    if (cnt > 0) { m0 = s0 / (float)cnt; m1 = s1 / (float)cnt; }
    unsigned int packed = (unsigned int)f2bf(m0) | ((unsigned int)f2bf(m1) << 16);
    ((unsigned int*)meanbb)[(size_t)row * (En / 2) + lane] = packed;
}

// ---------------- kernel 3: GEMM1, fused gather, 3-buffer depth-2 pipeline ----------------
// Tile 128(M) x 128(H) x 32(K), 40 iters. vmcnt(4) fine waits, raw barrier.
// LDS: 3*(8+8)+5 = 53 KB -> 3 blocks/CU.
__global__ __launch_bounds__(256, 3) void gemm1_kernel(
        const unsigned short* __restrict__ encb, const unsigned short* __restrict__ meanbb,
        const int* __restrict__ idxb, const unsigned short* __restrict__ w1b,
        const float* __restrict__ b1, unsigned short* __restrict__ hbuf) {
    __shared__ alignas(16) unsigned short As[3][128 * 32];   // 3 x 8 KB
    __shared__ alignas(16) unsigned short Bs[3][128 * 32];   // 3 x 8 KB
    __shared__ int idxs[128 * Kn];                           // 5 KB

    // XCD-aware remap: 5 h-blocks of one m-block consecutive per XCD.
    const int p = blockIdx.x;
    const int L = (p & 7) * 313 + (p >> 3);
    if (L >= (Mn / 128) * (H1n / 128)) return;
    const int row0 = (L / 5) * 128;
    const int h0   = (L % 5) * 128;

    const int t    = threadIdx.x;
    const int lane = t & 63;
    const int wave = t >> 6;
    const int ln15 = lane & 15;
    const int q4   = lane >> 4;
    const int wm   = wave & 1;
    const int wn   = wave >> 1;

    for (int i = t; i < 128 * Kn; i += 256) idxs[i] = idxb[row0 * Kn + i];

    // staging: row stride 32 ushorts (64 B = 4 x 16B slots). lane -> row rl=lane>>2,
    // slot sc=lane&3; slot sc of row r holds source chunk sc^((r>>1)&3)
    // -> fragment read (chunk q4) hits slot q4^((r>>1)&3): 2-way banks (free).
    const int rl   = lane >> 2;
    const int sc   = lane & 3;
    const int coff = (sc ^ ((rl >> 1) & 3)) * 8;   // source chunk offset (shorts)

    int lrow[2];
    const unsigned short* encB[2];
    const unsigned short* meanR[2];
    const unsigned short* w1R[2];
#pragma unroll
    for (int s = 0; s < 2; ++s) {
        lrow[s] = wave * 32 + s * 16 + rl;
        const int gr = row0 + lrow[s];
        const int bb = gr / Rn;
        encB[s]  = encb + (size_t)bb * Nn * En;
        meanR[s] = meanbb + (size_t)gr * En + coff;
        w1R[s]   = w1b + (size_t)(h0 + lrow[s]) * KEn + coff;
    }

    f32x4 acc[4][4];
#pragma unroll
    for (int i = 0; i < 4; ++i)
#pragma unroll
        for (int j = 0; j < 4; ++j)
            acc[i][j] = (f32x4){0.f, 0.f, 0.f, 0.f};

    auto issue = [&](int itk, int pb) {   // 4 DMAs per wave
        const int j   = itk >> 2;
        const int e0  = (itk & 3) * 32;
        const int kk0 = itk * 32;
#pragma unroll
        for (int s = 0; s < 2; ++s) {
            const int id = idxs[lrow[s] * Kn + j];
            const unsigned short* srcA = (id < Nn)
                ? (encB[s] + (size_t)id * En + e0 + coff)
                : (meanR[s] + e0);
            gl2lds16(srcA, &As[pb][(wave * 32 + s * 16) * 32]);
            gl2lds16(w1R[s] + kk0, &Bs[pb][(wave * 32 + s * 16) * 32]);
        }
    };

    __syncthreads();          // idxs visible
    issue(0, 0);
    issue(1, 1);

    const int NT = KEn / 32;  // 40
    const int sw = ((ln15 >> 1) & 3);
    int cb = 0;
    for (int itk = 0; itk < NT; ++itk) {
        if (itk < NT - 1) wait_vm4(); else wait_vm0();   // stage itk landed
        barrier_raw();                                    // visible to all waves
        if (itk + 2 < NT) {
            int pb = cb + 2; if (pb >= 3) pb -= 3;
            issue(itk + 2, pb);
        }
        s16x8 af[4], bf[4];
#pragma unroll
        for (int i = 0; i < 4; ++i) {
            const int r = wm * 64 + i * 16 + ln15;
            af[i] = *(const s16x8*)&As[cb][r * 32 + (q4 ^ sw) * 8];
        }
#pragma unroll
        for (int jj = 0; jj < 4; ++jj) {
            const int r = wn * 64 + jj * 16 + ln15;
            bf[jj] = *(const s16x8*)&Bs[cb][r * 32 + (q4 ^ sw) * 8];
        }
#pragma unroll
        for (int i = 0; i < 4; ++i)
#pragma unroll
            for (int jj = 0; jj < 4; ++jj)
                acc[i][jj] = __builtin_amdgcn_mfma_f32_16x16x32_bf16(af[i], bf[jj], acc[i][jj], 0, 0, 0);
        cb = (cb == 2) ? 0 : cb + 1;
    }

    // ---- epilogue: bias + relu + bf16 store ----
#pragma unroll
    for (int i = 0; i < 4; ++i) {
#pragma unroll
        for (int jj = 0; jj < 4; ++jj) {
            const int h = h0 + wn * 64 + jj * 16 + ln15;
            const float bias = b1[h];
#pragma unroll
            for (int rg = 0; rg < 4; ++rg) {
                const int m = wm * 64 + i * 16 + q4 * 4 + rg;
                float vv = acc[i][jj][rg] + bias;
                vv = fmaxf(vv, 0.f);
                hbuf[(size_t)(row0 + m) * H1n + h] = f2bf(vv);
            }
        }
    }
}

// ---------------- kernel 4: GEMM2, 3-buffer depth-2 pipeline ----------------
__global__ __launch_bounds__(256, 3) void gemm2_kernel(
        const unsigned short* __restrict__ hbuf, const unsigned short* __restrict__ w2b,
        const float* __restrict__ b2, float* __restrict__ out) {
    __shared__ alignas(16) unsigned short As[3][128 * 32];
    __shared__ alignas(16) unsigned short Bs[3][128 * 32];

    const int row0 = blockIdx.x * 128;
    const int t    = threadIdx.x;
    const int lane = t & 63;
    const int wave = t >> 6;
    const int ln15 = lane & 15;
    const int q4   = lane >> 4;
    const int wm   = wave & 1;
    const int wn   = wave >> 1;

    const int rl   = lane >> 2;
    const int sc   = lane & 3;
    const int coff = (sc ^ ((rl >> 1) & 3)) * 8;

    const unsigned short* hrow[2];
    const unsigned short* w2row[2];
#pragma unroll
    for (int s = 0; s < 2; ++s) {
        const int lr = wave * 32 + s * 16 + rl;
        hrow[s]  = hbuf + (size_t)(row0 + lr) * H1n + coff;
        w2row[s] = w2b + (size_t)lr * H1n + coff;
    }

    f32x4 acc[4][4];
#pragma unroll
    for (int i = 0; i < 4; ++i)
#pragma unroll
        for (int j = 0; j < 4; ++j)
            acc[i][j] = (f32x4){0.f, 0.f, 0.f, 0.f};

    auto issue = [&](int itk, int pb) {
        const int kk0 = itk * 32;
#pragma unroll
        for (int s = 0; s < 2; ++s) {
            gl2lds16(hrow[s] + kk0, &As[pb][(wave * 32 + s * 16) * 32]);
            gl2lds16(w2row[s] + kk0, &Bs[pb][(wave * 32 + s * 16) * 32]);
        }
    };

    issue(0, 0);
    issue(1, 1);

    const int NT = H1n / 32;  // 20
    const int sw = ((ln15 >> 1) & 3);
    int cb = 0;
    for (int itk = 0; itk < NT; ++itk) {
        if (itk < NT - 1) wait_vm4(); else wait_vm0();
        barrier_raw();
        if (itk + 2 < NT) {
            int pb = cb + 2; if (pb >= 3) pb -= 3;
            issue(itk + 2, pb);
        }
        s16x8 af[4], bf[4];
#pragma unroll
        for (int i = 0; i < 4; ++i) {
            const int r = wm * 64 + i * 16 + ln15;
            af[i] = *(const s16x8*)&As[cb][r * 32 + (q4 ^ sw) * 8];
        }
#pragma unroll
        for (int jj = 0; jj < 4; ++jj) {
            const int r = wn * 64 + jj * 16 + ln15;
            bf[jj] = *(const s16x8*)&Bs[cb][r * 32 + (q4 ^ sw) * 8];
        }
#pragma unroll
        for (int i = 0; i < 4; ++i)
#pragma unroll
            for (int jj = 0; jj < 4; ++jj)
                acc[i][jj] = __builtin_amdgcn_mfma_f32_16x16x32_bf16(af[i], bf[jj], acc[i][jj], 0, 0, 0);
        cb = (cb == 2) ? 0 : cb + 1;
    }

#pragma unroll
    for (int i = 0; i < 4; ++i) {
#pragma unroll
        for (int jj = 0; jj < 4; ++jj) {
            const int e = wn * 64 + jj * 16 + ln15;
            const float bias = b2[e];
#pragma unroll
            for (int rg = 0; rg < 4; ++rg) {
                const int m = wm * 64 + i * 16 + q4 * 4 + rg;
                out[(size_t)(row0 + m) * En + e] = acc[i][jj][rg] + bias;
            }
        }
    }
}

// ---------------- launch ----------------
extern "C" void kernel_launch(void* const* d_in, const int* in_sizes, int n_in,
                              void* d_out, int out_size, void* d_ws, size_t ws_size,
                              hipStream_t stream) {
    const int*   current  = (const int*)d_in[0];
    const float* distance = (const float*)d_in[1];
    const float* masked   = (const float*)d_in[2];
    const float* encoded  = (const float*)d_in[3];
    const float* w1       = (const float*)d_in[4];
    const float* b1       = (const float*)d_in[5];
    const float* w2       = (const float*)d_in[6];
    const float* b2       = (const float*)d_in[7];
    float* out = (float*)d_out;

    char* ws = (char*)d_ws;
    const size_t OFF_IDX  = 0;
    const size_t OFF_ENCB = 2560000;
    const size_t OFF_MEAN = OFF_ENCB + 16384000;
    const size_t OFF_W1B  = OFF_MEAN + 16384000;
    const size_t OFF_W2B  = OFF_W1B + 1638400;
    const size_t OFF_H    = OFF_W2B + 163840;
    int*            idxb   = (int*)(ws + OFF_IDX);
    unsigned short* encb   = (unsigned short*)(ws + OFF_ENCB);
    unsigned short* meanbb = (unsigned short*)(ws + OFF_MEAN);
    unsigned short* w1b    = (unsigned short*)(ws + OFF_W1B);
    unsigned short* w2b    = (unsigned short*)(ws + OFF_W2B);
    unsigned short* hbuf   = (unsigned short*)(ws + OFF_H);

    convw_kernel<<<(Bn * Nn * En / 4 + 255) / 256, 256, 0, stream>>>(encoded, w1, w2, encb, w1b, w2b);
    select_kernel<<<Mn / 4, 256, 0, stream>>>(current, distance, masked, encb, idxb, meanbb);
    gemm1_kernel<<<2504, 256, 0, stream>>>(encb, meanbb, idxb, w1b, b1, hbuf);
    gemm2_kernel<<<Mn / 128, 256, 0, stream>>>(hbuf, w2b, b2, out);
}